// Round 25
// baseline (47.661 us; speedup 1.0000x reference)
//
#include <hip/hip_runtime.h>
#include <hip/hip_bf16.h>

// SNN "SynapticChain": B=4, T=24, N=4096, F=32, L=3 (+1 final synaptic layer).
// R25: R24 + ONE structural change: tile DEFERRED one time-block.
// tile(tb-1) is issued at the TOP of iteration tb, before chain(tb) -- the
// two are fully independent (masks double-buffered by tb parity in mlds),
// so the compile-time scheduler can interleave tile MFMA/stores into the
// chain's lgkmcnt stall shadows (in-order issue per wave makes SOURCE-level
// independence the prerequisite for overlap). R19 tried this placement but
// was poisoned by weight remat; since R22 weights live in LDS wfrag.
// All arithmetic byte-identical to R24 (chain LAW intact; tile math R19/R22
// proven). Epilogue: tile(11).

namespace {
constexpr int kB = 4;
constexpr int kT = 24;
constexpr int kN = 4096;
constexpr int kF = 32;
constexpr int kNF = kN * kF;

typedef __attribute__((ext_vector_type(8))) short short8v;
typedef __attribute__((ext_vector_type(4))) float float4v;
typedef __attribute__((ext_vector_type(2))) float float2v;

__device__ __forceinline__ short bfc(float f) {
    return (short)__bfloat16_as_ushort(__float2bfloat16(f));
}
__device__ __forceinline__ float bfc_back(short s) {
    return __bfloat162float(__ushort_as_bfloat16((unsigned short)s));
}
__device__ __forceinline__ float uni(float v) {
    return __int_as_float(__builtin_amdgcn_readfirstlane(__float_as_int(v)));
}
__device__ __forceinline__ constexpr int kmap(int lg, int e) {
    return (e < 4) ? (lg * 4 + e) : (16 + lg * 4 + (e - 4));
}

__global__ __launch_bounds__(512, 2)
void snn_fused(const float* __restrict__ x,
               const float* __restrict__ alphas,
               const float* __restrict__ betas,
               const float* __restrict__ thrs,
               const float* __restrict__ chain_W,
               const float* __restrict__ chain_b,
               const float* __restrict__ lin_W,
               const float* __restrict__ lin_b,
               const float* __restrict__ W1,
               const float* __restrict__ b1,
               const float* __restrict__ prelu_a,
               const float* __restrict__ W2,
               const float* __restrict__ b2,
               float* __restrict__ out)
{
    const int tid  = threadIdx.x;
    const int lane = tid & 63;
    const int wid  = tid >> 6;              // 0..7
    const int r    = lane >> 3;             // chain: row within wave 0..7
    const int q    = lane & 7;              // chain: feature quad id 0..7
    const int l16  = lane & 15;             // mfma row/col
    const int lg   = lane >> 4;             // mfma 0..3

    const int base = (blockIdx.x * 8 + wid) * 8;    // wave's 8 bn-rows
    const int row  = base + r;
    const int b    = row >> 12;
    const int n    = row & (kN - 1);
    const int bq   = base >> 12;
    const int n0   = base & (kN - 1);

    __shared__ float    lutQ[3][8][16][8][4];  // 48 KB (chain, R22/R24 layout)
    __shared__ short8v  wfrag[12][64];         // 12 KB  (tile weights, kmap)
    __shared__ unsigned mlds[8][2][2][8];      // 1 KB   (masks [tb&1][tt][r])

    // ---- LUT build: same arithmetic as R12/R17/R20, permuted layout
#pragma unroll
    for (int c = 0; c < 2; ++c) {
        const int idx = tid + c * 512;
        if (idx < 768) {
            const int mat = idx >> 8;
            const int g   = (idx >> 5) & 7;
            const int jj  = idx & 31;
            const float* wsrc = chain_W + ((mat * kF + jj) * kF + g * 4);
            const float4 w = *reinterpret_cast<const float4*>(wsrc);
            const float bias = (g == 0) ? chain_b[mat * kF + jj] : 0.0f;
            float s[16];
            s[0]  = 0.0f;
            s[1]  = w.x;         s[2]  = w.y;         s[3]  = w.x + w.y;
            s[4]  = w.z;         s[5]  = w.x + w.z;   s[6]  = w.y + w.z;
            s[7]  = s[3] + w.z;  s[8]  = w.w;         s[9]  = w.x + w.w;
            s[10] = w.y + w.w;   s[11] = s[3] + w.w;  s[12] = w.z + w.w;
            s[13] = s[5] + w.w;  s[14] = s[6] + w.w;  s[15] = s[7] + w.w;
#pragma unroll
            for (int nb = 0; nb < 16; ++nb)
                lutQ[mat][g][nb][jj & 7][jj >> 3] = s[nb] + bias;
        }
    }

    // ---- tile weight fragments -> LDS in KMAP order
#pragma unroll
    for (int c = 0; c < 2; ++c) {
        const int idx = tid + c * 512;
        if (idx < 768) {
            const int f     = idx >> 6;
            const int lane2 = idx & 63;
            const int l16b  = lane2 & 15, lgb = lane2 >> 4;
            short8v fr;
            if (f < 4) {
                const int cc = f >> 1, sp = f & 1;
#pragma unroll
                for (int e = 0; e < 8; ++e) {
                    const float w  = lin_W[(cc * 16 + l16b) * 32 + kmap(lgb, e)];
                    const short s0 = bfc(w);
                    fr[e] = sp ? bfc(w - bfc_back(s0)) : s0;
                }
            } else if (f < 8) {
                const int c0 = f - 4;
#pragma unroll
                for (int e = 0; e < 8; ++e)
                    fr[e] = bfc(W1[(c0 * 16 + l16b) * 32 + kmap(lgb, e)]);
            } else {
                const int c2 = (f - 8) >> 1, kb = (f - 8) & 1;
#pragma unroll
                for (int e = 0; e < 8; ++e)
                    fr[e] = bfc(W2[(c2 * 16 + l16b) * 64 + kb * 32 + kmap(lgb, e)]);
            }
            wfrag[f][lane2] = fr;
        }
    }
    __syncthreads();

    // ---- uniform scalars -> SGPR
    float al[4], be[4], th[4];
#pragma unroll
    for (int i = 0; i < 4; ++i) {
        al[i] = uni(fminf(fmaxf(alphas[i], 0.0f), 1.0f));
        be[i] = uni(fminf(fmaxf(betas[i],  0.0f), 1.0f));
        th[i] = uni(thrs[i]);
    }
    const float pa = uni(prelu_a[0]);

    // ---- chain state (R20 layout: [layer][slot], feature j = q + 8*slot)
    float syn[4][4], mem[4][4];
#pragma unroll
    for (int i = 0; i < 4; ++i)
#pragma unroll
        for (int s = 0; s < 4; ++s) { syn[i][s] = 0.0f; mem[i][s] = 0.0f; }

    const float* xp = x + (size_t)(b * kT * kN + n) * kF + q;

    float xv[4];
#pragma unroll
    for (int s = 0; s < 4; ++s) xv[s] = xp[8 * s];

    // ---- all-register tile (R19/R22 body) for deferred time-block tbp
    auto tile = [&](int tbp) {
        const unsigned m = mlds[wid][tbp & 1][l16 >> 3][l16 & 7];
        short8v aspk;
#pragma unroll
        for (int e = 0; e < 8; ++e)
            aspk[e] = ((m >> kmap(lg, e)) & 1u) ? (short)0x3F80 : (short)0;

        // lin_out^T: A = lin_W frags (double-split), B = spikes
        const float4 lb0 = *reinterpret_cast<const float4*>(lin_b + lg * 4);
        const float4 lb1 = *reinterpret_cast<const float4*>(lin_b + 16 + lg * 4);
        float4v t0 = {lb0.x, lb0.y, lb0.z, lb0.w};
        float4v t1 = {lb1.x, lb1.y, lb1.z, lb1.w};
        t0 = __builtin_amdgcn_mfma_f32_16x16x32_bf16(wfrag[0][lane], aspk, t0, 0, 0, 0);
        t0 = __builtin_amdgcn_mfma_f32_16x16x32_bf16(wfrag[1][lane], aspk, t0, 0, 0, 0);
        t1 = __builtin_amdgcn_mfma_f32_16x16x32_bf16(wfrag[2][lane], aspk, t1, 0, 0, 0);
        t1 = __builtin_amdgcn_mfma_f32_16x16x32_bf16(wfrag[3][lane], aspk, t1, 0, 0, 0);

        // T -> hi/lo B-fragments
        short8v thi, tlo;
#pragma unroll
        for (int e = 0; e < 4; ++e) {
            const short h0 = bfc(t0[e]);
            thi[e] = h0; tlo[e] = bfc(t0[e] - bfc_back(h0));
            const short h1 = bfc(t1[e]);
            thi[4 + e] = h1; tlo[4 + e] = bfc(t1[e] - bfc_back(h1));
        }

        // layer1^T + prelu
        float g[16];
#pragma unroll
        for (int q4 = 0; q4 < 4; ++q4) {
            const float4 b14 = *reinterpret_cast<const float4*>(b1 + q4 * 16 + lg * 4);
            float4v c = {b14.x, b14.y, b14.z, b14.w};
            const short8v wf = wfrag[4 + q4][lane];
            c = __builtin_amdgcn_mfma_f32_16x16x32_bf16(wf, thi, c, 0, 0, 0);
            c = __builtin_amdgcn_mfma_f32_16x16x32_bf16(wf, tlo, c, 0, 0, 0);
#pragma unroll
            for (int rr = 0; rr < 4; ++rr) {
                const float v = c[rr];
                g[q4 * 4 + rr] = (v > 0.0f) ? v : pa * v;
            }
        }

        // G -> hi/lo B-fragments per kb
        short8v gh[2], gl[2];
#pragma unroll
        for (int kb = 0; kb < 2; ++kb)
#pragma unroll
            for (int e = 0; e < 8; ++e) {
                const float v = g[kb * 8 + e];
                const short h0 = bfc(v);
                gh[kb][e] = h0;
                gl[kb][e] = bfc(v - bfc_back(h0));
            }

        // layer2^T + store
        const size_t orow =
            ((size_t)(bq * kT + tbp * 2 + (l16 >> 3)) * kN + (n0 + (l16 & 7))) * kF;
#pragma unroll
        for (int oq = 0; oq < 2; ++oq) {
            const float4 b24 = *reinterpret_cast<const float4*>(b2 + oq * 16 + lg * 4);
            float4v o = {b24.x, b24.y, b24.z, b24.w};
            o = __builtin_amdgcn_mfma_f32_16x16x32_bf16(wfrag[8 + oq * 2 + 0][lane], gh[0], o, 0, 0, 0);
            o = __builtin_amdgcn_mfma_f32_16x16x32_bf16(wfrag[8 + oq * 2 + 0][lane], gl[0], o, 0, 0, 0);
            o = __builtin_amdgcn_mfma_f32_16x16x32_bf16(wfrag[8 + oq * 2 + 1][lane], gh[1], o, 0, 0, 0);
            o = __builtin_amdgcn_mfma_f32_16x16x32_bf16(wfrag[8 + oq * 2 + 1][lane], gl[1], o, 0, 0, 0);
            float4 st = {o[0], o[1], o[2], o[3]};
            *reinterpret_cast<float4*>(out + orow + oq * 16 + lg * 4) = st;
        }
    };

    for (int tb = 0; tb < 12; ++tb) {
        // ======== deferred tile(tb-1): independent of chain(tb) ===========
        if (tb > 0) tile(tb - 1);

        // ======== 2 chain steps (spike math byte-identical to R20/R24) =====
        for (int tt = 0; tt < 2; ++tt) {
            const int t = tb * 2 + tt;
            float xn[4] = {0.f, 0.f, 0.f, 0.f};
            if (t + 1 < kT) {
#pragma unroll
                for (int s = 0; s < 4; ++s) xn[s] = xp[(size_t)(t + 1) * kNF + 8 * s];
            }

            float hh[4];
#pragma unroll
            for (int s = 0; s < 4; ++s) hh[s] = xv[s];

#pragma unroll
            for (int i = 0; i < 4; ++i) {
                bool sp[4];
#pragma unroll
                for (int s = 0; s < 4; ++s) {
                    const float rst = ((mem[i][s] - th[i]) > 0.0f) ? 1.0f : 0.0f;
                    syn[i][s] = al[i] * syn[i][s] + hh[s];
                    mem[i][s] = be[i] * mem[i][s] + syn[i][s] - rst * th[i];
                    sp[s] = (mem[i][s] - th[i]) > 0.0f;
                }
                unsigned long long bal0 = __ballot(sp[0]);
                unsigned long long bal1 = __ballot(sp[1]);
                unsigned long long bal2 = __ballot(sp[2]);
                unsigned long long bal3 = __ballot(sp[3]);
                const unsigned f0 = (unsigned)((bal0 >> (r * 8)) & 0xFFull);
                const unsigned f1 = (unsigned)((bal1 >> (r * 8)) & 0xFFull);
                const unsigned f2 = (unsigned)((bal2 >> (r * 8)) & 0xFFull);
                const unsigned f3 = (unsigned)((bal3 >> (r * 8)) & 0xFFull);
                const unsigned m32 = f0 | (f1 << 8) | (f2 << 16) | (f3 << 24);

                if (i < 3) {
                    float4v vv[8];
#pragma unroll
                    for (int g = 0; g < 8; ++g) {
                        const unsigned nib = (m32 >> (4 * g)) & 15u;
                        vv[g] = *reinterpret_cast<const float4v*>(&lutQ[i][g][nib][q][0]);
                    }
                    // packed add tree (bitwise-identical per element, R24)
                    float2v lo[8], hi[8];
#pragma unroll
                    for (int g = 0; g < 8; ++g) {
                        lo[g] = __builtin_shufflevector(vv[g], vv[g], 0, 1);
                        hi[g] = __builtin_shufflevector(vv[g], vv[g], 2, 3);
                    }
                    const float2v a01 = ((lo[0] + lo[1]) + (lo[2] + lo[3]))
                                      + ((lo[4] + lo[5]) + (lo[6] + lo[7]));
                    const float2v a23 = ((hi[0] + hi[1]) + (hi[2] + hi[3]))
                                      + ((hi[4] + hi[5]) + (hi[6] + hi[7]));
                    hh[0] = a01[0]; hh[1] = a01[1];
                    hh[2] = a23[0]; hh[3] = a23[1];
                } else if (q == 0) {
                    mlds[wid][tb & 1][tt][r] = m32;   // mask, parity-buffered
                }
            }

#pragma unroll
            for (int s = 0; s < 4; ++s) xv[s] = xn[s];
        }
    }
    tile(11);
}
} // namespace

extern "C" void kernel_launch(void* const* d_in, const int* in_sizes, int n_in,
                              void* d_out, int out_size, void* d_ws, size_t ws_size,
                              hipStream_t stream) {
    const float* x        = (const float*)d_in[0];
    const float* alphas   = (const float*)d_in[1];
    const float* betas    = (const float*)d_in[2];
    const float* thrs     = (const float*)d_in[3];
    const float* chain_W  = (const float*)d_in[4];
    const float* chain_b  = (const float*)d_in[5];
    const float* lin_W    = (const float*)d_in[6];
    const float* lin_b    = (const float*)d_in[7];
    const float* W1       = (const float*)d_in[8];
    const float* b1       = (const float*)d_in[9];
    const float* prelu_a  = (const float*)d_in[10];
    const float* W2       = (const float*)d_in[11];
    const float* b2       = (const float*)d_in[12];
    float* out            = (float*)d_out;

    // 256 blocks * 8 waves * 8 rows = 16384 rows; fused chain + deferred tile
    hipLaunchKernelGGL(snn_fused, dim3(256), dim3(512), 0, stream,
                       x, alphas, betas, thrs, chain_W, chain_b, lin_W, lin_b,
                       W1, b1, prelu_a, W2, b2, out);
}

// Round 26
// 44.681 us; speedup vs baseline: 1.0667x; 1.0667x over previous
//
#include <hip/hip_runtime.h>
#include <hip/hip_bf16.h>

// SNN "SynapticChain": B=4, T=24, N=4096, F=32, L=3 (+1 final synaptic layer).
// R26 = R24 REVERT (proven 44.9us). R25's deferred tile regressed (47.7us):
// VGPR 96->68 + VALUBusy 49->42% show the allocator split the tile's live
// ranges across the chain block (remat/LDS re-reads) instead of interleaving
// -- same failure mode as R19. Chain->tile adjacency is the regalloc sweet
// spot. Ledger: occupancy x3 null, ILP +25%, split +55%, fusion +21%,
// all-reg tile +6%, pad -1.5% (rev), packed adds +5%, defer -6% (rev).
// Chain: lutQ b128 (bank group=q, free same-nib broadcasts), packed-add
// tree (bitwise-identical), recurrence byte-identical since R12 (LAW).
// Tile: all-register transposed MFMA (kmap), weights in LDS wfrag.

namespace {
constexpr int kB = 4;
constexpr int kT = 24;
constexpr int kN = 4096;
constexpr int kF = 32;
constexpr int kNF = kN * kF;

typedef __attribute__((ext_vector_type(8))) short short8v;
typedef __attribute__((ext_vector_type(4))) float float4v;
typedef __attribute__((ext_vector_type(2))) float float2v;

__device__ __forceinline__ short bfc(float f) {
    return (short)__bfloat16_as_ushort(__float2bfloat16(f));
}
__device__ __forceinline__ float bfc_back(short s) {
    return __bfloat162float(__ushort_as_bfloat16((unsigned short)s));
}
__device__ __forceinline__ float uni(float v) {
    return __int_as_float(__builtin_amdgcn_readfirstlane(__float_as_int(v)));
}
__device__ __forceinline__ constexpr int kmap(int lg, int e) {
    return (e < 4) ? (lg * 4 + e) : (16 + lg * 4 + (e - 4));
}

__global__ __launch_bounds__(512, 2)
void snn_fused(const float* __restrict__ x,
               const float* __restrict__ alphas,
               const float* __restrict__ betas,
               const float* __restrict__ thrs,
               const float* __restrict__ chain_W,
               const float* __restrict__ chain_b,
               const float* __restrict__ lin_W,
               const float* __restrict__ lin_b,
               const float* __restrict__ W1,
               const float* __restrict__ b1,
               const float* __restrict__ prelu_a,
               const float* __restrict__ W2,
               const float* __restrict__ b2,
               float* __restrict__ out)
{
    const int tid  = threadIdx.x;
    const int lane = tid & 63;
    const int wid  = tid >> 6;              // 0..7
    const int r    = lane >> 3;             // chain: row within wave 0..7
    const int q    = lane & 7;              // chain: feature quad id 0..7
    const int l16  = lane & 15;             // mfma row/col
    const int lg   = lane >> 4;             // mfma 0..3

    const int base = (blockIdx.x * 8 + wid) * 8;    // wave's 8 bn-rows
    const int row  = base + r;
    const int b    = row >> 12;
    const int n    = row & (kN - 1);
    const int bq   = base >> 12;
    const int n0   = base & (kN - 1);

    __shared__ float    lutQ[3][8][16][8][4];  // 48 KB (chain, R20/R22 layout)
    __shared__ short8v  wfrag[12][64];         // 12 KB  (tile weights, kmap)
    __shared__ unsigned mlds[8][2][8];         // 512 B  (masks [tt][r])

    // ---- LUT build: same arithmetic as R12/R17/R20, permuted layout
#pragma unroll
    for (int c = 0; c < 2; ++c) {
        const int idx = tid + c * 512;
        if (idx < 768) {
            const int mat = idx >> 8;
            const int g   = (idx >> 5) & 7;
            const int jj  = idx & 31;
            const float* wsrc = chain_W + ((mat * kF + jj) * kF + g * 4);
            const float4 w = *reinterpret_cast<const float4*>(wsrc);
            const float bias = (g == 0) ? chain_b[mat * kF + jj] : 0.0f;
            float s[16];
            s[0]  = 0.0f;
            s[1]  = w.x;         s[2]  = w.y;         s[3]  = w.x + w.y;
            s[4]  = w.z;         s[5]  = w.x + w.z;   s[6]  = w.y + w.z;
            s[7]  = s[3] + w.z;  s[8]  = w.w;         s[9]  = w.x + w.w;
            s[10] = w.y + w.w;   s[11] = s[3] + w.w;  s[12] = w.z + w.w;
            s[13] = s[5] + w.w;  s[14] = s[6] + w.w;  s[15] = s[7] + w.w;
#pragma unroll
            for (int nb = 0; nb < 16; ++nb)
                lutQ[mat][g][nb][jj & 7][jj >> 3] = s[nb] + bias;
        }
    }

    // ---- tile weight fragments -> LDS in KMAP order (A-side of transposed
    // layers). frag 0..3: lin_W (c=f>>1, split=f&1, double-split);
    // frag 4..7: W1 row-block; frag 8..11: W2 [oq][kb].
#pragma unroll
    for (int c = 0; c < 2; ++c) {
        const int idx = tid + c * 512;
        if (idx < 768) {
            const int f     = idx >> 6;
            const int lane2 = idx & 63;
            const int l16b  = lane2 & 15, lgb = lane2 >> 4;
            short8v fr;
            if (f < 4) {
                const int cc = f >> 1, sp = f & 1;
#pragma unroll
                for (int e = 0; e < 8; ++e) {
                    const float w  = lin_W[(cc * 16 + l16b) * 32 + kmap(lgb, e)];
                    const short s0 = bfc(w);
                    fr[e] = sp ? bfc(w - bfc_back(s0)) : s0;
                }
            } else if (f < 8) {
                const int c0 = f - 4;
#pragma unroll
                for (int e = 0; e < 8; ++e)
                    fr[e] = bfc(W1[(c0 * 16 + l16b) * 32 + kmap(lgb, e)]);
            } else {
                const int c2 = (f - 8) >> 1, kb = (f - 8) & 1;
#pragma unroll
                for (int e = 0; e < 8; ++e)
                    fr[e] = bfc(W2[(c2 * 16 + l16b) * 64 + kb * 32 + kmap(lgb, e)]);
            }
            wfrag[f][lane2] = fr;
        }
    }
    __syncthreads();

    // ---- uniform scalars -> SGPR (value-identical; VGPR relief)
    float al[4], be[4], th[4];
#pragma unroll
    for (int i = 0; i < 4; ++i) {
        al[i] = uni(fminf(fmaxf(alphas[i], 0.0f), 1.0f));
        be[i] = uni(fminf(fmaxf(betas[i],  0.0f), 1.0f));
        th[i] = uni(thrs[i]);
    }
    const float pa = uni(prelu_a[0]);

    // ---- chain state (R20 layout: [layer][slot], feature j = q + 8*slot)
    float syn[4][4], mem[4][4];
#pragma unroll
    for (int i = 0; i < 4; ++i)
#pragma unroll
        for (int s = 0; s < 4; ++s) { syn[i][s] = 0.0f; mem[i][s] = 0.0f; }

    const float* xp = x + (size_t)(b * kT * kN + n) * kF + q;

    float xv[4];
#pragma unroll
    for (int s = 0; s < 4; ++s) xv[s] = xp[8 * s];

    for (int tb = 0; tb < 12; ++tb) {
        // ======== 2 chain steps (spike math byte-identical to R20/R22) =====
        for (int tt = 0; tt < 2; ++tt) {
            const int t = tb * 2 + tt;
            float xn[4] = {0.f, 0.f, 0.f, 0.f};
            if (t + 1 < kT) {
#pragma unroll
                for (int s = 0; s < 4; ++s) xn[s] = xp[(size_t)(t + 1) * kNF + 8 * s];
            }

            float hh[4];
#pragma unroll
            for (int s = 0; s < 4; ++s) hh[s] = xv[s];

#pragma unroll
            for (int i = 0; i < 4; ++i) {
                bool sp[4];
#pragma unroll
                for (int s = 0; s < 4; ++s) {
                    const float rst = ((mem[i][s] - th[i]) > 0.0f) ? 1.0f : 0.0f;
                    syn[i][s] = al[i] * syn[i][s] + hh[s];
                    mem[i][s] = be[i] * mem[i][s] + syn[i][s] - rst * th[i];
                    sp[s] = (mem[i][s] - th[i]) > 0.0f;
                }
                unsigned long long bal0 = __ballot(sp[0]);
                unsigned long long bal1 = __ballot(sp[1]);
                unsigned long long bal2 = __ballot(sp[2]);
                unsigned long long bal3 = __ballot(sp[3]);
                const unsigned f0 = (unsigned)((bal0 >> (r * 8)) & 0xFFull);
                const unsigned f1 = (unsigned)((bal1 >> (r * 8)) & 0xFFull);
                const unsigned f2 = (unsigned)((bal2 >> (r * 8)) & 0xFFull);
                const unsigned f3 = (unsigned)((bal3 >> (r * 8)) & 0xFFull);
                const unsigned m32 = f0 | (f1 << 8) | (f2 << 16) | (f3 << 24);

                if (i < 3) {
                    float4v vv[8];
#pragma unroll
                    for (int g = 0; g < 8; ++g) {
                        const unsigned nib = (m32 >> (4 * g)) & 15u;
                        vv[g] = *reinterpret_cast<const float4v*>(&lutQ[i][g][nib][q][0]);
                    }
                    // packed add tree: slots (0,1) and (2,3) as float2.
                    // Per-element association identical to the scalar tree
                    // -> bitwise-identical hh (v_pk_add_f32 = 2 IEEE adds).
                    float2v lo[8], hi[8];
#pragma unroll
                    for (int g = 0; g < 8; ++g) {
                        lo[g] = __builtin_shufflevector(vv[g], vv[g], 0, 1);
                        hi[g] = __builtin_shufflevector(vv[g], vv[g], 2, 3);
                    }
                    const float2v a01 = ((lo[0] + lo[1]) + (lo[2] + lo[3]))
                                      + ((lo[4] + lo[5]) + (lo[6] + lo[7]));
                    const float2v a23 = ((hi[0] + hi[1]) + (hi[2] + hi[3]))
                                      + ((hi[4] + hi[5]) + (hi[6] + hi[7]));
                    hh[0] = a01[0]; hh[1] = a01[1];
                    hh[2] = a23[0]; hh[3] = a23[1];
                } else if (q == 0) {
                    mlds[wid][tt][r] = m32;   // layer-3 mask, row r, parity tt
                }
            }

#pragma unroll
            for (int s = 0; s < 4; ++s) xv[s] = xn[s];
        }

        // ======== all-register tile (R19 body): 8 rows x 2 t ==============
        // tile row = l16: bn = base + (l16&7), t = tb*2 + (l16>>3)
        const unsigned m = mlds[wid][l16 >> 3][l16 & 7];
        short8v aspk;
#pragma unroll
        for (int e = 0; e < 8; ++e)
            aspk[e] = ((m >> kmap(lg, e)) & 1u) ? (short)0x3F80 : (short)0;

        // lin_out^T: A = lin_W frags (double-split), B = spikes
        const float4 lb0 = *reinterpret_cast<const float4*>(lin_b + lg * 4);
        const float4 lb1 = *reinterpret_cast<const float4*>(lin_b + 16 + lg * 4);
        float4v t0 = {lb0.x, lb0.y, lb0.z, lb0.w};
        float4v t1 = {lb1.x, lb1.y, lb1.z, lb1.w};
        t0 = __builtin_amdgcn_mfma_f32_16x16x32_bf16(wfrag[0][lane], aspk, t0, 0, 0, 0);
        t0 = __builtin_amdgcn_mfma_f32_16x16x32_bf16(wfrag[1][lane], aspk, t0, 0, 0, 0);
        t1 = __builtin_amdgcn_mfma_f32_16x16x32_bf16(wfrag[2][lane], aspk, t1, 0, 0, 0);
        t1 = __builtin_amdgcn_mfma_f32_16x16x32_bf16(wfrag[3][lane], aspk, t1, 0, 0, 0);

        // T -> hi/lo B-fragments (slot e<4 from t0[e], e>=4 from t1[e-4])
        short8v thi, tlo;
#pragma unroll
        for (int e = 0; e < 4; ++e) {
            const short h0 = bfc(t0[e]);
            thi[e] = h0; tlo[e] = bfc(t0[e] - bfc_back(h0));
            const short h1 = bfc(t1[e]);
            thi[4 + e] = h1; tlo[4 + e] = bfc(t1[e] - bfc_back(h1));
        }

        // layer1^T + prelu: g[q4*4+r] = G[l16][q4*16+lg*4+r]
        float g[16];
#pragma unroll
        for (int q4 = 0; q4 < 4; ++q4) {
            const float4 b14 = *reinterpret_cast<const float4*>(b1 + q4 * 16 + lg * 4);
            float4v c = {b14.x, b14.y, b14.z, b14.w};
            const short8v wf = wfrag[4 + q4][lane];
            c = __builtin_amdgcn_mfma_f32_16x16x32_bf16(wf, thi, c, 0, 0, 0);
            c = __builtin_amdgcn_mfma_f32_16x16x32_bf16(wf, tlo, c, 0, 0, 0);
#pragma unroll
            for (int rr = 0; rr < 4; ++rr) {
                const float v = c[rr];
                g[q4 * 4 + rr] = (v > 0.0f) ? v : pa * v;
            }
        }

        // G -> hi/lo B-fragments per kb (slot e <-> g[kb*8+e])
        short8v gh[2], gl[2];
#pragma unroll
        for (int kb = 0; kb < 2; ++kb)
#pragma unroll
            for (int e = 0; e < 8; ++e) {
                const float v = g[kb * 8 + e];
                const short h0 = bfc(v);
                gh[kb][e] = h0;
                gl[kb][e] = bfc(v - bfc_back(h0));
            }

        // layer2^T + store: lane holds out[l16][oq*16+lg*4+r] -> float4
        const size_t orow =
            ((size_t)(bq * kT + tb * 2 + (l16 >> 3)) * kN + (n0 + (l16 & 7))) * kF;
#pragma unroll
        for (int oq = 0; oq < 2; ++oq) {
            const float4 b24 = *reinterpret_cast<const float4*>(b2 + oq * 16 + lg * 4);
            float4v o = {b24.x, b24.y, b24.z, b24.w};
            o = __builtin_amdgcn_mfma_f32_16x16x32_bf16(wfrag[8 + oq * 2 + 0][lane], gh[0], o, 0, 0, 0);
            o = __builtin_amdgcn_mfma_f32_16x16x32_bf16(wfrag[8 + oq * 2 + 0][lane], gl[0], o, 0, 0, 0);
            o = __builtin_amdgcn_mfma_f32_16x16x32_bf16(wfrag[8 + oq * 2 + 1][lane], gh[1], o, 0, 0, 0);
            o = __builtin_amdgcn_mfma_f32_16x16x32_bf16(wfrag[8 + oq * 2 + 1][lane], gl[1], o, 0, 0, 0);
            float4 st = {o[0], o[1], o[2], o[3]};
            *reinterpret_cast<float4*>(out + orow + oq * 16 + lg * 4) = st;
        }
    }
}
} // namespace

extern "C" void kernel_launch(void* const* d_in, const int* in_sizes, int n_in,
                              void* d_out, int out_size, void* d_ws, size_t ws_size,
                              hipStream_t stream) {
    const float* x        = (const float*)d_in[0];
    const float* alphas   = (const float*)d_in[1];
    const float* betas    = (const float*)d_in[2];
    const float* thrs     = (const float*)d_in[3];
    const float* chain_W  = (const float*)d_in[4];
    const float* chain_b  = (const float*)d_in[5];
    const float* lin_W    = (const float*)d_in[6];
    const float* lin_b    = (const float*)d_in[7];
    const float* W1       = (const float*)d_in[8];
    const float* b1       = (const float*)d_in[9];
    const float* prelu_a  = (const float*)d_in[10];
    const float* W2       = (const float*)d_in[11];
    const float* b2       = (const float*)d_in[12];
    float* out            = (float*)d_out;

    // 256 blocks * 8 waves * 8 rows = 16384 rows; fused chain + all-reg tile
    hipLaunchKernelGGL(snn_fused, dim3(256), dim3(512), 0, stream,
                       x, alphas, betas, thrs, chain_W, chain_b, lin_W, lin_b,
                       W1, b1, prelu_a, W2, b2, out);
}